// Round 1
// baseline (858.889 us; speedup 1.0000x reference)
//
#include <hip/hip_runtime.h>
#include <stdint.h>

#define TOKENS 4096
#define DIM    1024
#define HDIM   4096
#define NEXP   8
#define NPAD   5120
#define ALPHA  0.001f
#define BETA   0.001f
#define GAMMA  0.001f

// ---- workspace layout (bytes) ----
#define WS_CNT      0          // int[8]
#define WS_SUMP     32         // float[8]
#define WS_PSUM     64         // float[8]
#define WS_PSUMSQ   96         // float[8]
#define WS_OFFP     128        // int[16] (use 9)
#define WS_AVGP     192        // float[8]
#define WS_LOSSP    224        // float[1]
#define WS_OFFSQ    256        // float[8]
#define WS_HDR_END  512
#define WS_YNORM    512                    // float[5120]  -> 20992
#define WS_LIST     21504                  // int[8*4096]  -> 152576
#define WS_XB       152576                 // bf16[4096*1024]   -> 8541184
#define WS_W1T      8541184                // bf16[8*4096*1024] -> 75650048
#define WS_W2T      75650048               // bf16[8*1024*4096] -> 142758912
#define WS_HBUF     142758912              // bf16[5120*4096]   -> 184701952
#define WS_YT       184701952              // bf16[1024*5120]   -> 195187712
#define WS_TOTAL    195187712

typedef __bf16 bf16x8 __attribute__((ext_vector_type(8)));
typedef float  f32x4  __attribute__((ext_vector_type(4)));
typedef unsigned short u16x4 __attribute__((ext_vector_type(4)));

__device__ __forceinline__ unsigned short f2bf(float f) {
    union { float f; unsigned u; } v; v.f = f;
    unsigned r = v.u + 0x7fffu + ((v.u >> 16) & 1u);   // RNE
    return (unsigned short)(r >> 16);
}
__device__ __forceinline__ float bf2f(unsigned short h) {
    union { unsigned u; float f; } v; v.u = ((unsigned)h) << 16;
    return v.f;
}

// ---------------- K0a: x f32 -> bf16 ----------------
__global__ void k_cvt_x(const float* __restrict__ x, unsigned short* __restrict__ xb) {
    const int n4 = TOKENS * DIM / 4;
    for (int i = blockIdx.x * blockDim.x + threadIdx.x; i < n4; i += gridDim.x * blockDim.x) {
        float4 v = ((const float4*)x)[i];
        u16x4 o;
        o[0] = f2bf(v.x); o[1] = f2bf(v.y); o[2] = f2bf(v.z); o[3] = f2bf(v.w);
        ((u16x4*)xb)[i] = o;
    }
}

// ---------------- K0b: transpose + cvt  (out[c][r] = in[r][c]) ----------------
__global__ void k_transpose_cvt(const float* __restrict__ in, unsigned short* __restrict__ out,
                                int R, int C) {
    __shared__ float tile[32][33];
    const float* inp = in + (size_t)blockIdx.z * R * C;
    unsigned short* outp = out + (size_t)blockIdx.z * R * C;
    int r0 = blockIdx.y * 32, c0 = blockIdx.x * 32;
    int tx = threadIdx.x & 31, ty = threadIdx.x >> 5;  // 256 thr: ty 0..7
#pragma unroll
    for (int j = 0; j < 4; j++)
        tile[ty + 8 * j][tx] = inp[(size_t)(r0 + ty + 8 * j) * C + c0 + tx];
    __syncthreads();
#pragma unroll
    for (int j = 0; j < 4; j++)
        outp[(size_t)(c0 + ty + 8 * j) * R + r0 + tx] = f2bf(tile[tx][ty + 8 * j]);
}

// ---------------- K1: gating ----------------
__global__ __launch_bounds__(1024) void k_gate(
        const float* __restrict__ x, const float* __restrict__ gw, const float* __restrict__ gb,
        int* __restrict__ cnt, float* __restrict__ sump,
        float* __restrict__ psum, float* __restrict__ psumsq, int* __restrict__ list) {
    __shared__ float gwT[NEXP * DIM];
    __shared__ float bacc[3 * NEXP];
    int tid = threadIdx.x;
    if (tid < 3 * NEXP) bacc[tid] = 0.f;
    for (int i = tid; i < DIM * NEXP; i += 1024) {
        int d = i >> 3, e = i & 7;
        gwT[e * DIM + d] = gw[i];
    }
    __syncthreads();
    int wv = tid >> 6, l = tid & 63;
    int t = blockIdx.x * 16 + wv;
    float acc[8];
#pragma unroll
    for (int e = 0; e < 8; e++) acc[e] = 0.f;
    const float* xr = x + (size_t)t * DIM;
#pragma unroll
    for (int j = 0; j < 16; j++) {
        float xv = xr[l + 64 * j];
#pragma unroll
        for (int e = 0; e < 8; e++) acc[e] += xv * gwT[e * DIM + l + 64 * j];
    }
#pragma unroll
    for (int e = 0; e < 8; e++) {
#pragma unroll
        for (int s = 32; s > 0; s >>= 1) acc[e] += __shfl_xor(acc[e], s);
    }
    if (l == 0) {
        float lg[8], mx = -1e30f;
#pragma unroll
        for (int e = 0; e < 8; e++) { lg[e] = acc[e] + gb[e]; mx = fmaxf(mx, lg[e]); }
        float p[8], se = 0.f;
#pragma unroll
        for (int e = 0; e < 8; e++) { p[e] = __expf(lg[e] - mx); se += p[e]; }
        float inv = 1.f / se;
        int arg = 0; float best = lg[0];
#pragma unroll
        for (int e = 1; e < 8; e++) if (lg[e] > best) { best = lg[e]; arg = e; }
        float ptop = p[arg] * inv;
        int pos = atomicAdd(&cnt[arg], 1);
        list[arg * TOKENS + pos] = t;
        atomicAdd(&bacc[arg], ptop);
#pragma unroll
        for (int e = 0; e < 8; e++) {
            float pe = p[e] * inv;
            atomicAdd(&bacc[8 + e], pe);
            atomicAdd(&bacc[16 + e], pe * pe);
        }
    }
    __syncthreads();
    if (tid < 8) {
        atomicAdd(&sump[tid], bacc[tid]);
        atomicAdd(&psum[tid], bacc[8 + tid]);
        atomicAdd(&psumsq[tid], bacc[16 + tid]);
    }
}

// ---------------- K2: finalize gating ----------------
__global__ void k_finalize_gate(const int* __restrict__ cnt, const float* __restrict__ sump,
                                const float* __restrict__ psum, const float* __restrict__ psumsq,
                                int* __restrict__ offp, float* __restrict__ avgp,
                                float* __restrict__ lossp) {
    if (threadIdx.x == 0) {
        int off = 0; float aux = 0.f, var = 0.f;
        for (int e = 0; e < 8; e++) {
            offp[e] = off;
            int c = cnt[e];
            off += ((c + 127) / 128) * 128;
            float cf = (float)c;
            avgp[e] = (c > 0) ? sump[e] / cf : 0.f;
            float u = cf / (float)TOKENS;
            aux += u * u;
            var += psumsq[e] - psum[e] * psum[e] / (float)TOKENS;
        }
        offp[8] = off;
        aux *= (float)NEXP;
        float varloss = -var / ((float)TOKENS * (float)NEXP);
        lossp[0] = ALPHA * aux + GAMMA * varloss;
    }
}

// ---------------- K3: GEMM1  H = relu(X_e @ w1[e] + b1[e]) ----------------
__global__ __launch_bounds__(256) void k_gemm1(
        const unsigned short* __restrict__ xb, const unsigned short* __restrict__ w1t,
        const float* __restrict__ b1, const int* __restrict__ cnt, const int* __restrict__ offp,
        const int* __restrict__ list, unsigned short* __restrict__ Hbuf) {
    int e = blockIdx.z, rt = blockIdx.y, ct = blockIdx.x;
    int cnt_e = cnt[e];
    int row0 = rt * 128;
    if (row0 >= cnt_e) return;
    int offe = offp[e];
    __shared__ unsigned short ldsA[128 * 32];
    __shared__ unsigned short ldsB[128 * 32];
    int tid = threadIdx.x, wv = tid >> 6, l = tid & 63;
    int wr = wv >> 1, wc = wv & 1;
    int r0s = l, r1s = 64 + l;
    int t0 = list[e * TOKENS + min(row0 + r0s, cnt_e - 1)];
    int t1 = list[e * TOKENS + min(row0 + r1s, cnt_e - 1)];
    const unsigned short* srcA0 = xb + (size_t)t0 * DIM + wv * 8;
    const unsigned short* srcA1 = xb + (size_t)t1 * DIM + wv * 8;
    const unsigned short* srcB0 = w1t + ((size_t)e * HDIM + ct * 128 + r0s) * DIM + wv * 8;
    const unsigned short* srcB1 = w1t + ((size_t)e * HDIM + ct * 128 + r1s) * DIM + wv * 8;
    f32x4 acc[4][4] = {};
    for (int kk = 0; kk < DIM; kk += 32) {
        bf16x8 va0 = *(const bf16x8*)(srcA0 + kk);
        bf16x8 va1 = *(const bf16x8*)(srcA1 + kk);
        bf16x8 vb0 = *(const bf16x8*)(srcB0 + kk);
        bf16x8 vb1 = *(const bf16x8*)(srcB1 + kk);
        __syncthreads();
        *(bf16x8*)(ldsA + (wv * 128 + l) * 8)      = va0;
        *(bf16x8*)(ldsA + (wv * 128 + 64 + l) * 8) = va1;
        *(bf16x8*)(ldsB + (wv * 128 + l) * 8)      = vb0;
        *(bf16x8*)(ldsB + (wv * 128 + 64 + l) * 8) = vb1;
        __syncthreads();
        int g = l >> 4, rr = l & 15;
        bf16x8 a[4], b[4];
#pragma unroll
        for (int m = 0; m < 4; m++) a[m] = *(const bf16x8*)(ldsA + (g * 128 + wr * 64 + m * 16 + rr) * 8);
#pragma unroll
        for (int n = 0; n < 4; n++) b[n] = *(const bf16x8*)(ldsB + (g * 128 + wc * 64 + n * 16 + rr) * 8);
#pragma unroll
        for (int m = 0; m < 4; m++)
#pragma unroll
            for (int n = 0; n < 4; n++)
                acc[m][n] = __builtin_amdgcn_mfma_f32_16x16x32_bf16(a[m], b[n], acc[m][n], 0, 0, 0);
    }
    int g = l >> 4, rr = l & 15;
#pragma unroll
    for (int n = 0; n < 4; n++) {
        int colg = ct * 128 + wc * 64 + n * 16 + rr;
        float bv = b1[e * HDIM + colg];
#pragma unroll
        for (int m = 0; m < 4; m++) {
#pragma unroll
            for (int j = 0; j < 4; j++) {
                int rloc = row0 + wr * 64 + m * 16 + g * 4 + j;
                if (rloc < cnt_e) {
                    float v = fmaxf(acc[m][n][j] + bv, 0.f);
                    Hbuf[(size_t)(offe + rloc) * HDIM + colg] = f2bf(v);
                }
            }
        }
    }
}

// ---------------- K4: GEMM2  y = H_e @ w2[e] + b2; out scatter; yT write ----------------
__global__ __launch_bounds__(256) void k_gemm2(
        const unsigned short* __restrict__ Hbuf, const unsigned short* __restrict__ w2t,
        const float* __restrict__ b2, const int* __restrict__ cnt, const int* __restrict__ offp,
        const int* __restrict__ list, const float* __restrict__ avgp,
        float* __restrict__ out, unsigned short* __restrict__ yT) {
    int e = blockIdx.z, rt = blockIdx.y, ct = blockIdx.x;   // ct: 0..7
    int cnt_e = cnt[e];
    int row0 = rt * 128;
    if (row0 >= cnt_e) return;
    int offe = offp[e];
    __shared__ unsigned short ldsA[128 * 32];
    __shared__ unsigned short ldsB[128 * 32];
    int tid = threadIdx.x, wv = tid >> 6, l = tid & 63;
    int wr = wv >> 1, wc = wv & 1;
    int r0s = l, r1s = 64 + l;
    const unsigned short* srcA0 = Hbuf + (size_t)(offe + row0 + r0s) * HDIM + wv * 8;
    const unsigned short* srcA1 = Hbuf + (size_t)(offe + row0 + r1s) * HDIM + wv * 8;
    const unsigned short* srcB0 = w2t + ((size_t)e * DIM + ct * 128 + r0s) * HDIM + wv * 8;
    const unsigned short* srcB1 = w2t + ((size_t)e * DIM + ct * 128 + r1s) * HDIM + wv * 8;
    f32x4 acc[4][4] = {};
    for (int kk = 0; kk < HDIM; kk += 32) {
        bf16x8 va0 = *(const bf16x8*)(srcA0 + kk);
        bf16x8 va1 = *(const bf16x8*)(srcA1 + kk);
        bf16x8 vb0 = *(const bf16x8*)(srcB0 + kk);
        bf16x8 vb1 = *(const bf16x8*)(srcB1 + kk);
        __syncthreads();
        *(bf16x8*)(ldsA + (wv * 128 + l) * 8)      = va0;
        *(bf16x8*)(ldsA + (wv * 128 + 64 + l) * 8) = va1;
        *(bf16x8*)(ldsB + (wv * 128 + l) * 8)      = vb0;
        *(bf16x8*)(ldsB + (wv * 128 + 64 + l) * 8) = vb1;
        __syncthreads();
        int g = l >> 4, rr = l & 15;
        bf16x8 a[4], b[4];
#pragma unroll
        for (int m = 0; m < 4; m++) a[m] = *(const bf16x8*)(ldsA + (g * 128 + wr * 64 + m * 16 + rr) * 8);
#pragma unroll
        for (int n = 0; n < 4; n++) b[n] = *(const bf16x8*)(ldsB + (g * 128 + wc * 64 + n * 16 + rr) * 8);
#pragma unroll
        for (int m = 0; m < 4; m++)
#pragma unroll
            for (int n = 0; n < 4; n++)
                acc[m][n] = __builtin_amdgcn_mfma_f32_16x16x32_bf16(a[m], b[n], acc[m][n], 0, 0, 0);
    }
    float ap = avgp[e];
    int g = l >> 4, rr = l & 15;
#pragma unroll
    for (int m = 0; m < 4; m++) {
        int rbase = row0 + wr * 64 + m * 16 + g * 4;
        int toks[4]; bool lv[4];
#pragma unroll
        for (int j = 0; j < 4; j++) {
            int rl = rbase + j;
            lv[j] = rl < cnt_e;
            toks[j] = lv[j] ? list[e * TOKENS + rl] : 0;
        }
#pragma unroll
        for (int n = 0; n < 4; n++) {
            int colg = ct * 128 + wc * 64 + n * 16 + rr;
            float bv = b2[e * DIM + colg];
            u16x4 pk;
#pragma unroll
            for (int j = 0; j < 4; j++) {
                float yv = acc[m][n][j] + bv;
                if (lv[j]) {
                    out[(size_t)toks[j] * DIM + colg] = ap * yv;
                    pk[j] = f2bf(yv);
                } else {
                    pk[j] = 0;
                }
            }
            *(u16x4*)(yT + (size_t)colg * NPAD + offe + rbase) = pk;
        }
    }
}

// ---------------- K4b: row norms s_n = sum_d y^2 ----------------
__global__ void k_ynorm(const unsigned short* __restrict__ yT, float* __restrict__ ynorm) {
    int n = blockIdx.x * blockDim.x + threadIdx.x;
    if (n >= NPAD) return;
    float s = 0.f;
    for (int d = 0; d < DIM; d++) {
        float v = bf2f(yT[(size_t)d * NPAD + n]);
        s += v * v;
    }
    ynorm[n] = s;
}

// ---------------- K5: Gram  ||Y^T Y||_F^2 per expert ----------------
__global__ __launch_bounds__(256) void k_gram(
        const unsigned short* __restrict__ yT, const int* __restrict__ cnt,
        const int* __restrict__ offp, float* __restrict__ offsq) {
    int e = blockIdx.z, dt = blockIdx.y, ct = blockIdx.x;
    int cnt_e = cnt[e];
    if (cnt_e <= 0) return;
    int offe = offp[e];
    int ksteps = (cnt_e + 31) / 32;
    __shared__ unsigned short ldsA[128 * 32];
    __shared__ unsigned short ldsB[128 * 32];
    __shared__ float wsum[4];
    int tid = threadIdx.x, wv = tid >> 6, l = tid & 63;
    int wr = wv >> 1, wc = wv & 1;
    int r0s = l, r1s = 64 + l;
    const unsigned short* srcA0 = yT + (size_t)(dt * 128 + r0s) * NPAD + offe + wv * 8;
    const unsigned short* srcA1 = yT + (size_t)(dt * 128 + r1s) * NPAD + offe + wv * 8;
    const unsigned short* srcB0 = yT + (size_t)(ct * 128 + r0s) * NPAD + offe + wv * 8;
    const unsigned short* srcB1 = yT + (size_t)(ct * 128 + r1s) * NPAD + offe + wv * 8;
    f32x4 acc[4][4] = {};
    for (int ks = 0; ks < ksteps; ks++) {
        int kk = ks * 32;
        bf16x8 va0 = *(const bf16x8*)(srcA0 + kk);
        bf16x8 va1 = *(const bf16x8*)(srcA1 + kk);
        bf16x8 vb0 = *(const bf16x8*)(srcB0 + kk);
        bf16x8 vb1 = *(const bf16x8*)(srcB1 + kk);
        __syncthreads();
        *(bf16x8*)(ldsA + (wv * 128 + l) * 8)      = va0;
        *(bf16x8*)(ldsA + (wv * 128 + 64 + l) * 8) = va1;
        *(bf16x8*)(ldsB + (wv * 128 + l) * 8)      = vb0;
        *(bf16x8*)(ldsB + (wv * 128 + 64 + l) * 8) = vb1;
        __syncthreads();
        int g = l >> 4, rr = l & 15;
        bf16x8 a[4], b[4];
#pragma unroll
        for (int m = 0; m < 4; m++) a[m] = *(const bf16x8*)(ldsA + (g * 128 + wr * 64 + m * 16 + rr) * 8);
#pragma unroll
        for (int n = 0; n < 4; n++) b[n] = *(const bf16x8*)(ldsB + (g * 128 + wc * 64 + n * 16 + rr) * 8);
#pragma unroll
        for (int m = 0; m < 4; m++)
#pragma unroll
            for (int n = 0; n < 4; n++)
                acc[m][n] = __builtin_amdgcn_mfma_f32_16x16x32_bf16(a[m], b[n], acc[m][n], 0, 0, 0);
    }
    float s = 0.f;
#pragma unroll
    for (int m = 0; m < 4; m++)
#pragma unroll
        for (int n = 0; n < 4; n++)
#pragma unroll
            for (int j = 0; j < 4; j++) s += acc[m][n][j] * acc[m][n][j];
#pragma unroll
    for (int sh = 32; sh > 0; sh >>= 1) s += __shfl_xor(s, sh);
    if (l == 0) wsum[wv] = s;
    __syncthreads();
    if (tid == 0) atomicAdd(&offsq[e], wsum[0] + wsum[1] + wsum[2] + wsum[3]);
}

// ---------------- K6: final loss ----------------
__global__ void k_loss(const int* __restrict__ cnt, const int* __restrict__ offp,
                       const float* __restrict__ offsq, const float* __restrict__ ynorm,
                       const float* __restrict__ lossp, float* __restrict__ out_loss) {
    __shared__ float ssq[8];
    int tid = threadIdx.x;
    if (tid < 8) ssq[tid] = 0.f;
    __syncthreads();
    int total = offp[8];
    for (int i = tid; i < total; i += blockDim.x) {
        int e = 0;
#pragma unroll
        for (int k = 0; k < 8; k++) if (i >= offp[k + 1]) e = k + 1;
        float s = ynorm[i];
        atomicAdd(&ssq[e], s * s);
    }
    __syncthreads();
    if (tid == 0) {
        float orth = 0.f;
        for (int e = 0; e < 8; e++) {
            if (cnt[e] > 0) {
                float cf = (float)cnt[e];
                orth += (offsq[e] - ssq[e]) / (cf * cf);
            }
        }
        out_loss[0] = lossp[0] + BETA * orth;
    }
}

extern "C" void kernel_launch(void* const* d_in, const int* in_sizes, int n_in,
                              void* d_out, int out_size, void* d_ws, size_t ws_size,
                              hipStream_t stream) {
    (void)in_sizes; (void)n_in; (void)out_size;
    const float* x  = (const float*)d_in[0];
    const float* gw = (const float*)d_in[1];
    const float* gb = (const float*)d_in[2];
    const float* w1 = (const float*)d_in[3];
    const float* b1 = (const float*)d_in[4];
    const float* w2 = (const float*)d_in[5];
    const float* b2 = (const float*)d_in[6];
    float* out = (float*)d_out;
    char* ws = (char*)d_ws;
    if (ws_size < (size_t)WS_TOTAL) return;

    int*   cnt    = (int*)(ws + WS_CNT);
    float* sump   = (float*)(ws + WS_SUMP);
    float* psum   = (float*)(ws + WS_PSUM);
    float* psumsq = (float*)(ws + WS_PSUMSQ);
    int*   offp   = (int*)(ws + WS_OFFP);
    float* avgp   = (float*)(ws + WS_AVGP);
    float* lossp  = (float*)(ws + WS_LOSSP);
    float* offsq  = (float*)(ws + WS_OFFSQ);
    float* ynorm  = (float*)(ws + WS_YNORM);
    int*   list   = (int*)(ws + WS_LIST);
    unsigned short* xb   = (unsigned short*)(ws + WS_XB);
    unsigned short* w1t  = (unsigned short*)(ws + WS_W1T);
    unsigned short* w2t  = (unsigned short*)(ws + WS_W2T);
    unsigned short* Hbuf = (unsigned short*)(ws + WS_HBUF);
    unsigned short* yT   = (unsigned short*)(ws + WS_YT);

    hipMemsetAsync(ws, 0, WS_HDR_END, stream);
    k_cvt_x<<<2048, 256, 0, stream>>>(x, xb);
    k_transpose_cvt<<<dim3(128, 32, 8), 256, 0, stream>>>(w1, w1t, 1024, 4096);
    k_transpose_cvt<<<dim3(32, 128, 8), 256, 0, stream>>>(w2, w2t, 4096, 1024);
    k_gate<<<256, 1024, 0, stream>>>(x, gw, gb, cnt, sump, psum, psumsq, list);
    k_finalize_gate<<<1, 64, 0, stream>>>(cnt, sump, psum, psumsq, offp, avgp, lossp);
    k_gemm1<<<dim3(32, 32, 8), 256, 0, stream>>>(xb, w1t, b1, cnt, offp, list, Hbuf);
    k_gemm2<<<dim3(8, 32, 8), 256, 0, stream>>>(Hbuf, w2t, b2, cnt, offp, list, avgp, out, yT);
    k_ynorm<<<20, 256, 0, stream>>>(yT, ynorm);
    k_gram<<<dim3(8, 8, 8), 256, 0, stream>>>(yT, cnt, offp, offsq);
    k_loss<<<1, 256, 0, stream>>>(cnt, offp, offsq, ynorm, lossp, out + (size_t)TOKENS * DIM);
}